// Round 17
// baseline (984.638 us; speedup 1.0000x reference)
//
#include <hip/hip_runtime.h>

#define GD 130              // grid extent per dim (G+2)
#define GD2 (GD*GD)
#define GRID_ELEMS (GD*GD*GD)
#define STATS_BYTES 1024
#define WPB 16              // waves per conv block (1024 threads)
#define CONV_BLOCKS 256
#define MAX_NIN 100000
#define MAX_NOUT 1600000

typedef _Float16 f16x8 __attribute__((ext_vector_type(8)));
typedef float    f32x4 __attribute__((ext_vector_type(4)));

__device__ _Float16 g_feat16[(MAX_NIN + 1) * 32];      // +1 zero row at idx n_in
__device__ _Float16 g_out16[(size_t)MAX_NOUT * 64];    // interleaved: pos p -> chan (p, p+32)

__device__ __forceinline__ f32x4 mfma16(uint4 a, uint4 b, f32x4 c) {
    union { uint4 u; f16x8 h; } A, B;
    A.u = a; B.u = b;
    return __builtin_amdgcn_mfma_f32_16x16x32_f16(A.h, B.h, c, 0, 0, 0);
}

__global__ __launch_bounds__(256) void scatter_grid_k(
    const int* __restrict__ pos, int* __restrict__ grid, int n_in)
{
    int i = blockIdx.x * blockDim.x + threadIdx.x;
    if (i < n_in) {
        int x = pos[3*i], y = pos[3*i+1], z = pos[3*i+2];
        grid[(x*GD + y)*GD + z] = i;
    }
}

__global__ __launch_bounds__(256) void feat_to_f16_k(
    const float* __restrict__ feat, int n_in)
{
    int i = (blockIdx.x * blockDim.x + threadIdx.x) * 8;
    const int ntot = (n_in + 1) * 32;
    if (i < ntot) {
        union { _Float16 h[8]; uint4 u; } t;
        if (i < n_in * 32) {
            const float4 a = *reinterpret_cast<const float4*>(feat + i);
            const float4 b = *reinterpret_cast<const float4*>(feat + i + 4);
            t.h[0] = (_Float16)a.x; t.h[1] = (_Float16)a.y;
            t.h[2] = (_Float16)a.z; t.h[3] = (_Float16)a.w;
            t.h[4] = (_Float16)b.x; t.h[5] = (_Float16)b.y;
            t.h[6] = (_Float16)b.z; t.h[7] = (_Float16)b.w;
        } else {
            t.u = uint4{0u, 0u, 0u, 0u};                 // zero row (idx = n_in)
        }
        *reinterpret_cast<uint4*>(g_feat16 + i) = t.u;
    }
}

// unaligned 16B probe: grid[base..base+2] used (.x/.y/.z), .w discarded
__device__ __forceinline__ int4 probe4(const int* __restrict__ grid, int base) {
    int4 p;
    __builtin_memcpy(&p, grid + base, 16);
    return p;
}

__device__ __forceinline__ int sel3(int4 p, int dz) {
    return dz == 0 ? p.x : (dz == 1 ? p.y : p.z);
}

// MFMA sparse conv with 16x16x32 fragments:
//  - one probe4 per (dx,dy) covers all 64 rows (lane = row)
//  - per tap: idx redistributed to row-groups via __shfl (LDS pipe, not TA)
//  - A gather: 4 k-lanes of a row hit the SAME 64B line in ONE instruction
//    -> each feat line touched once per tap (half of the 32x32 scheme)
__global__ __launch_bounds__(1024) void conv_mfma_k(
    const float* __restrict__ W,
    const int* __restrict__ outpos, const int* __restrict__ grid,
    float* __restrict__ stats, int n_out, int n_in)
{
    __shared__ uint4 wlds[27*4*64];     // [tap][cg][lane] = 110,592 B
    __shared__ float sstat[128];

    const int tid  = threadIdx.x;
    const int lane = tid & 63;
    const int wid  = tid >> 6;
    const int lo   = lane & 15;         // row-in-group / col-in-group
    const int kc   = lane >> 4;         // k-chunk 0..3

    // stage W: global [k][cin][cout] f32 -> wlds[t][cg][lane]:
    //   .h[j] = W[t][(lane>>4)*8 + j][cg*16 + (lane&15)]  (f16)
    for (int g = tid; g < 27*4*64; g += 1024) {
        const int t   = g >> 8;
        const int rem = g & 255;
        const int cg  = rem >> 6;
        const int l   = rem & 63;
        const int kcs = l >> 4;
        const int co  = cg*16 + (l & 15);
        union { _Float16 h[8]; uint4 u; } w;
        #pragma unroll
        for (int j = 0; j < 8; ++j)
            w.h[j] = (_Float16)W[t*2048 + (kcs*8 + j)*64 + co];
        wlds[g] = w.u;
    }
    if (tid < 128) sstat[tid] = 0.f;
    __syncthreads();

    unsigned* g_o32 = reinterpret_cast<unsigned*>(g_out16);

    const int nchunks = (n_out + 63) >> 6;
    const int xcd  = blockIdx.x & 7;
    const int lw   = (blockIdx.x >> 3) * WPB + wid;   // 0..511 within XCD
    const int nlw  = (gridDim.x >> 3) * WPB;          // 512
    const int Q    = (nchunks + 7) >> 3;
    const int cLo  = xcd * Q;
    const int cHi  = min(cLo + Q, nchunks);

    float ssum[4] = {0.f, 0.f, 0.f, 0.f};
    float ssq[4]  = {0.f, 0.f, 0.f, 0.f};

    for (int ch = cLo + lw; ch < cHi; ch += nlw) {
        const int r0 = ch << 6;
        const int rb = min(r0 + lane, n_out - 1);     // lane = row
        int3 c;
        __builtin_memcpy(&c, outpos + 3*rb, 12);
        const int gb = (c.x*GD + c.y)*GD + c.z;

        f32x4 acc[4][4];                              // [rg][cg], static idx
        #pragma unroll
        for (int rg = 0; rg < 4; ++rg)
            #pragma unroll
            for (int cg = 0; cg < 4; ++cg)
                acc[rg][cg] = f32x4{0.f, 0.f, 0.f, 0.f};

        #pragma unroll
        for (int g = 0; g < 9; ++g) {
            const int off = (g/3)*GD2 + (g%3)*GD;
            const int4 p = probe4(grid, gb + off);
            #pragma unroll
            for (int dz = 0; dz < 3; ++dz) {
                const int t = g*3 + dz;
                const uint4 b0 = wlds[(t*4 + 0)*64 + lane];
                const uint4 b1 = wlds[(t*4 + 1)*64 + lane];
                const uint4 b2 = wlds[(t*4 + 2)*64 + lane];
                const uint4 b3 = wlds[(t*4 + 3)*64 + lane];
                const int v = sel3(p, dz);
                #pragma unroll
                for (int rg = 0; rg < 4; ++rg) {
                    const int idx = __shfl(v, lo + 16*rg, 64);
                    const int s = idx < 0 ? n_in : idx;
                    const uint4 a = *reinterpret_cast<const uint4*>(
                        g_feat16 + (size_t)s * 32 + kc * 8);
                    acc[rg][0] = mfma16(a, b0, acc[rg][0]);
                    acc[rg][1] = mfma16(a, b1, acc[rg][1]);
                    acc[rg][2] = mfma16(a, b2, acc[rg][2]);
                    acc[rg][3] = mfma16(a, b3, acc[rg][3]);
                }
            }
        }

        // epilogue: C layout col=lane&15, row=(lane>>4)*4+j (m89)
        // pack (chan cg*16+lo, chan +32) into u32 -> coalesced stores
        const bool full = (r0 + 64 <= n_out);
        #pragma unroll
        for (int rg = 0; rg < 4; ++rg) {
            #pragma unroll
            for (int j = 0; j < 4; ++j) {
                const int row = r0 + rg*16 + kc*4 + j;
                if (full || row < n_out) {
                    const float v0 = acc[rg][0][j], v1 = acc[rg][1][j];
                    const float v2 = acc[rg][2][j], v3 = acc[rg][3][j];
                    union { unsigned u; _Float16 h[2]; } q0, q1;
                    q0.h[0] = (_Float16)v0; q0.h[1] = (_Float16)v2;
                    q1.h[0] = (_Float16)v1; q1.h[1] = (_Float16)v3;
                    g_o32[(size_t)row * 32 + lo]      = q0.u;
                    g_o32[(size_t)row * 32 + 16 + lo] = q1.u;
                    ssum[0] += v0; ssq[0] = fmaf(v0, v0, ssq[0]);
                    ssum[1] += v1; ssq[1] = fmaf(v1, v1, ssq[1]);
                    ssum[2] += v2; ssq[2] = fmaf(v2, v2, ssq[2]);
                    ssum[3] += v3; ssq[3] = fmaf(v3, v3, ssq[3]);
                }
            }
        }
    }

    // channel of ssum[cg] = cg*16 + lo
    #pragma unroll
    for (int cg = 0; cg < 4; ++cg) {
        atomicAdd(&sstat[cg*16 + lo],      ssum[cg]);
        atomicAdd(&sstat[64 + cg*16 + lo], ssq[cg]);
    }
    __syncthreads();
    if (tid < 128) unsafeAtomicAdd(&stats[tid], sstat[tid]);
}

__global__ __launch_bounds__(256) void bn_relu_k(
    float* __restrict__ out, const float* __restrict__ stats,
    const float* __restrict__ gamma, const float* __restrict__ beta, int n_out)
{
    __shared__ float sc[64], sh[64];
    if (threadIdx.x < 64) {
        const int c = threadIdx.x;
        const double inv_n = 1.0 / (double)n_out;
        const double mean = (double)stats[c] * inv_n;
        const double var  = (double)stats[64 + c] * inv_n - mean * mean;
        const float scale = gamma[c] * rsqrtf((float)var + 1e-5f);
        sc[c] = scale;
        sh[c] = beta[c] - (float)mean * scale;
    }
    __syncthreads();

    // g_out16 interleaved: position p (0..63) within row -> channel (p>>1)+32*(p&1)
    const size_t total8 = (size_t)n_out * 8;
    for (size_t t = (size_t)blockIdx.x * blockDim.x + threadIdx.x;
         t < total8; t += (size_t)gridDim.x * blockDim.x) {
        union { uint4 u; _Float16 h[8]; } v;
        v.u = *reinterpret_cast<const uint4*>(g_out16 + t * 8);
        const int c0 = ((int)(t & 7)) * 4;          // channels c0..c0+3 and +32
        float4 r0, r1;
        r0.x = fmaxf(fmaf((float)v.h[0], sc[c0+0],    sh[c0+0]),    0.f);
        r1.x = fmaxf(fmaf((float)v.h[1], sc[c0+32],   sh[c0+32]),   0.f);
        r0.y = fmaxf(fmaf((float)v.h[2], sc[c0+1],    sh[c0+1]),    0.f);
        r1.y = fmaxf(fmaf((float)v.h[3], sc[c0+33],   sh[c0+33]),   0.f);
        r0.z = fmaxf(fmaf((float)v.h[4], sc[c0+2],    sh[c0+2]),    0.f);
        r1.z = fmaxf(fmaf((float)v.h[5], sc[c0+34],   sh[c0+34]),   0.f);
        r0.w = fmaxf(fmaf((float)v.h[6], sc[c0+3],    sh[c0+3]),    0.f);
        r1.w = fmaxf(fmaf((float)v.h[7], sc[c0+35],   sh[c0+35]),   0.f);
        float* rowp = out + (size_t)(t >> 3) * 64;
        *reinterpret_cast<float4*>(rowp + c0)      = r0;
        *reinterpret_cast<float4*>(rowp + 32 + c0) = r1;
    }
}

extern "C" void kernel_launch(void* const* d_in, const int* in_sizes, int n_in_arrs,
                              void* d_out, int out_size, void* d_ws, size_t ws_size,
                              hipStream_t stream)
{
    const float* feat   = (const float*)d_in[0];
    const float* W      = (const float*)d_in[1];
    const float* gamma  = (const float*)d_in[2];
    const float* beta   = (const float*)d_in[3];
    const int*   pos    = (const int*)d_in[4];
    const int*   outpos = (const int*)d_in[5];

    const int n_in  = in_sizes[0] / 32;
    const int n_out = in_sizes[5] / 3;

    float* out   = (float*)d_out;
    float* stats = (float*)d_ws;
    int*   grid  = (int*)((char*)d_ws + STATS_BYTES);

    hipMemsetAsync(stats, 0, STATS_BYTES, stream);
    // +4 pad ints: vectorized z-probe may read 12B past the last element
    hipMemsetAsync(grid, 0xFF, ((size_t)GRID_ELEMS + 4) * 4, stream);

    scatter_grid_k<<<(n_in + 255) / 256, 256, 0, stream>>>(pos, grid, n_in);
    feat_to_f16_k<<<((n_in + 1) * 4 + 255) / 256, 256, 0, stream>>>(feat, n_in);
    conv_mfma_k<<<CONV_BLOCKS, 1024, 0, stream>>>(W, outpos, grid, stats, n_out, n_in);
    bn_relu_k<<<2048, 256, 0, stream>>>(out, stats, gamma, beta, n_out);
}

// Round 18
// 360.675 us; speedup vs baseline: 2.7300x; 2.7300x over previous
//
#include <hip/hip_runtime.h>

#define GD 130              // grid extent per dim (G+2)
#define GD2 (GD*GD)
#define GRID_ELEMS (GD*GD*GD)
#define STATS_BYTES 1024
#define WPB 16              // waves per conv block (1024 threads)
#define CONV_BLOCKS 256
#define MAX_NIN 100000
#define MAX_NOUT 1600000
#define WSTRIDE 5           // padded granule stride (conflict-free, R5-verified)

typedef _Float16 f16x8 __attribute__((ext_vector_type(8)));
typedef float    f32x16 __attribute__((ext_vector_type(16)));

__device__ _Float16 g_feat16[(MAX_NIN + 1) * 32];      // +1 zero row at idx n_in
__device__ _Float16 g_out16[(size_t)MAX_NOUT * 64];    // interleaved: pos 2*oc+h -> chan oc+32*h

__device__ __forceinline__ f32x16 mfma_f16(uint4 a, uint4 b, f32x16 c) {
    union { uint4 u; f16x8 h; } A, B;
    A.u = a; B.u = b;
    return __builtin_amdgcn_mfma_f32_32x32x16_f16(A.h, B.h, c, 0, 0, 0);
}

// fused: scatter positions into grid AND convert features to f16 (+ zero row)
__global__ __launch_bounds__(256) void prep_k(
    const int* __restrict__ pos, int* __restrict__ grid,
    const float* __restrict__ feat, int n_in)
{
    const int i = blockIdx.x * blockDim.x + threadIdx.x;
    if (i < n_in) {
        const int x = pos[3*i], y = pos[3*i+1], z = pos[3*i+2];
        grid[(x*GD + y)*GD + z] = i;
    }
    const int f = i * 8;                      // 8 f16 per thread
    const int ntot = (n_in + 1) * 32;
    if (f < ntot) {
        union { _Float16 h[8]; uint4 u; } t;
        if (f < n_in * 32) {
            const float4 a = *reinterpret_cast<const float4*>(feat + f);
            const float4 b = *reinterpret_cast<const float4*>(feat + f + 4);
            t.h[0] = (_Float16)a.x; t.h[1] = (_Float16)a.y;
            t.h[2] = (_Float16)a.z; t.h[3] = (_Float16)a.w;
            t.h[4] = (_Float16)b.x; t.h[5] = (_Float16)b.y;
            t.h[6] = (_Float16)b.z; t.h[7] = (_Float16)b.w;
        } else {
            t.u = uint4{0u, 0u, 0u, 0u};                 // zero row (idx = n_in)
        }
        *reinterpret_cast<uint4*>(g_feat16 + f) = t.u;
    }
}

// MFMA sparse conv, XCD-contiguous chunk slabs, vectorized z-probes,
// (dx,dy)-group software pipelining, per-batch empty skip.  (R10 structure)
__global__ __launch_bounds__(1024, 4) void conv_mfma_k(
    const float* __restrict__ W,
    const int* __restrict__ outpos, const int* __restrict__ grid,
    float* __restrict__ stats, int n_out, int n_in)
{
    __shared__ uint4 wlds[27*64*WSTRIDE];   // 138,240 B
    __shared__ float sstat[128];

    const int tid  = threadIdx.x;
    const int lane = tid & 63;
    const int wid  = tid >> 6;
    const int oc   = lane & 31;
    const int hi   = lane >> 5;

    // stage W: global [k][cin][cout] f32 -> LDS [k][cout][granule] f16
    for (int g = tid; g < 27*64*4; g += 1024) {
        const int k   = g >> 8;
        const int rem = g & 255;
        const int o   = rem >> 2;
        const int q   = rem & 3;
        union { _Float16 h[8]; uint4 u; } t;
        #pragma unroll
        for (int j = 0; j < 8; ++j)
            t.h[j] = (_Float16)W[k*2048 + (q*8 + j)*64 + o];
        wlds[(k*64 + o)*WSTRIDE + q] = t.u;
    }
    if (tid < 128) sstat[tid] = 0.f;
    __syncthreads();

    unsigned* g_o32 = reinterpret_cast<unsigned*>(g_out16);

    const int nchunks = (n_out + 63) >> 6;
    // XCD-contiguous partition: xcd owns chunks [xcd*Q, xcd*Q+Q)
    const int xcd  = blockIdx.x & 7;
    const int lw   = (blockIdx.x >> 3) * WPB + wid;   // 0..511 within XCD
    const int nlw  = (gridDim.x >> 3) * WPB;          // 512
    const int Q    = (nchunks + 7) >> 3;
    const int cLo  = xcd * Q;
    const int cHi  = min(cLo + Q, nchunks);

    float ssum0 = 0.f, ssq0 = 0.f, ssum1 = 0.f, ssq1 = 0.f;

    for (int ch = cLo + lw; ch < cHi; ch += nlw) {
        const int r0 = ch << 6;
        const int rb0 = min(r0 + oc,      n_out - 1);
        const int rb1 = min(r0 + 32 + oc, n_out - 1);
        const int x0 = outpos[3*rb0], y0 = outpos[3*rb0+1], z0 = outpos[3*rb0+2];
        const int x1 = outpos[3*rb1], y1 = outpos[3*rb1+1], z1 = outpos[3*rb1+2];
        const int gb0 = (x0*GD + y0)*GD + z0;
        const int gb1 = (x1*GD + y1)*GD + z1;

        f32x16 acc00 = {0.f};   // batch0, couts 0..31
        f32x16 acc01 = {0.f};   // batch0, couts 32..63
        f32x16 acc10 = {0.f};   // batch1, couts 0..31
        f32x16 acc11 = {0.f};   // batch1, couts 32..63

        #pragma unroll
        for (int grp = 0; grp < 3; ++grp) {
            int id0[9], id1[9];
            #pragma unroll
            for (int i = 0; i < 9; ++i) {
                const int t  = grp*9 + i;
                const int dx = t / 9, dyz = t - 9*dx;
                const int dy = dyz / 3, dz = dyz - 3*dy;
                const int off = dx*GD2 + dy*GD + dz;
                id0[i] = grid[gb0 + off];
                id1[i] = grid[gb1 + off];
            }
            #pragma unroll
            for (int i = 0; i < 9; ++i) {
                const int t = grp*9 + i;
                const int wb = (t*64 + oc)*WSTRIDE + hi;
                const uint4 b00 = wlds[wb];
                const uint4 b10 = wlds[wb + 2];
                const uint4 b01 = wlds[wb + 32*WSTRIDE];
                const uint4 b11 = wlds[wb + 32*WSTRIDE + 2];
                {
                    const int s = id0[i] < 0 ? n_in : id0[i];
                    const uint4* fp = reinterpret_cast<const uint4*>(
                        g_feat16 + (size_t)s * 32);
                    const uint4 a0 = fp[hi], a1 = fp[2 + hi];
                    acc00 = mfma_f16(a0, b00, acc00);
                    acc00 = mfma_f16(a1, b10, acc00);
                    acc01 = mfma_f16(a0, b01, acc01);
                    acc01 = mfma_f16(a1, b11, acc01);
                }
                {
                    const int s = id1[i] < 0 ? n_in : id1[i];
                    const uint4* fp = reinterpret_cast<const uint4*>(
                        g_feat16 + (size_t)s * 32);
                    const uint4 a0 = fp[hi], a1 = fp[2 + hi];
                    acc10 = mfma_f16(a0, b00, acc10);
                    acc10 = mfma_f16(a1, b10, acc10);
                    acc11 = mfma_f16(a0, b01, acc11);
                    acc11 = mfma_f16(a1, b11, acc11);
                }
            }
        }

        // epilogue: C layout col=lane&31, row=(j&3)+8*(j>>2)+4*hi (m74/m101)
        // lane packs (chan oc, chan oc+32) into one u32 -> 128 B wave stores
        if (r0 + 64 <= n_out) {
            #pragma unroll
            for (int j = 0; j < 16; ++j) {
                const int rl = (j & 3) + 8*(j >> 2) + 4*hi;
                union { unsigned u; _Float16 h[2]; } p0, p1;
                const float v00 = acc00[j], v01 = acc01[j];
                const float v10 = acc10[j], v11 = acc11[j];
                p0.h[0] = (_Float16)v00; p0.h[1] = (_Float16)v01;
                p1.h[0] = (_Float16)v10; p1.h[1] = (_Float16)v11;
                g_o32[(size_t)(r0 + rl) * 32 + oc]      = p0.u;
                g_o32[(size_t)(r0 + 32 + rl) * 32 + oc] = p1.u;
                ssum0 += v00 + v10; ssq0 = fmaf(v00, v00, fmaf(v10, v10, ssq0));
                ssum1 += v01 + v11; ssq1 = fmaf(v01, v01, fmaf(v11, v11, ssq1));
            }
        } else {
            #pragma unroll
            for (int j = 0; j < 16; ++j) {
                const int rl = (j & 3) + 8*(j >> 2) + 4*hi;
                if (r0 + rl < n_out) {
                    const float v00 = acc00[j], v01 = acc01[j];
                    union { unsigned u; _Float16 h[2]; } p0;
                    p0.h[0] = (_Float16)v00; p0.h[1] = (_Float16)v01;
                    g_o32[(size_t)(r0 + rl) * 32 + oc] = p0.u;
                    ssum0 += v00; ssq0 = fmaf(v00, v00, ssq0);
                    ssum1 += v01; ssq1 = fmaf(v01, v01, ssq1);
                }
                if (r0 + 32 + rl < n_out) {
                    const float v10 = acc10[j], v11 = acc11[j];
                    union { unsigned u; _Float16 h[2]; } p1;
                    p1.h[0] = (_Float16)v10; p1.h[1] = (_Float16)v11;
                    g_o32[(size_t)(r0 + 32 + rl) * 32 + oc] = p1.u;
                    ssum0 += v10; ssq0 = fmaf(v10, v10, ssq0);
                    ssum1 += v11; ssq1 = fmaf(v11, v11, ssq1);
                }
            }
        }
    }

    atomicAdd(&sstat[oc],          ssum0);
    atomicAdd(&sstat[32 + oc],     ssum1);
    atomicAdd(&sstat[64 + oc],     ssq0);
    atomicAdd(&sstat[96 + oc],     ssq1);
    __syncthreads();
    // sstat: [0..31]=sum c0..31, [32..63]=sum c32..63, [64..95]=sq lo, [96..127]=sq hi
    if (tid < 128) unsafeAtomicAdd(&stats[tid], sstat[tid]);
}

__global__ __launch_bounds__(256) void bn_relu_k(
    float* __restrict__ out, const float* __restrict__ stats,
    const float* __restrict__ gamma, const float* __restrict__ beta, int n_out)
{
    __shared__ float sc[64], sh[64];
    if (threadIdx.x < 64) {
        const int c = threadIdx.x;
        const double inv_n = 1.0 / (double)n_out;
        const double mean = (double)stats[c] * inv_n;
        const double var  = (double)stats[64 + c] * inv_n - mean * mean;
        const float scale = gamma[c] * rsqrtf((float)var + 1e-5f);
        sc[c] = scale;
        sh[c] = beta[c] - (float)mean * scale;
    }
    __syncthreads();

    // g_out16 interleaved: position p (0..63) within row -> channel (p>>1)+32*(p&1)
    const size_t total8 = (size_t)n_out * 8;
    for (size_t t = (size_t)blockIdx.x * blockDim.x + threadIdx.x;
         t < total8; t += (size_t)gridDim.x * blockDim.x) {
        union { uint4 u; _Float16 h[8]; } v;
        v.u = *reinterpret_cast<const uint4*>(g_out16 + t * 8);
        const int c0 = ((int)(t & 7)) * 4;          // channels c0..c0+3 and +32
        float4 r0, r1;
        r0.x = fmaxf(fmaf((float)v.h[0], sc[c0+0],    sh[c0+0]),    0.f);
        r1.x = fmaxf(fmaf((float)v.h[1], sc[c0+32],   sh[c0+32]),   0.f);
        r0.y = fmaxf(fmaf((float)v.h[2], sc[c0+1],    sh[c0+1]),    0.f);
        r1.y = fmaxf(fmaf((float)v.h[3], sc[c0+33],   sh[c0+33]),   0.f);
        r0.z = fmaxf(fmaf((float)v.h[4], sc[c0+2],    sh[c0+2]),    0.f);
        r1.z = fmaxf(fmaf((float)v.h[5], sc[c0+34],   sh[c0+34]),   0.f);
        r0.w = fmaxf(fmaf((float)v.h[6], sc[c0+3],    sh[c0+3]),    0.f);
        r1.w = fmaxf(fmaf((float)v.h[7], sc[c0+35],   sh[c0+35]),   0.f);
        float* rowp = out + (size_t)(t >> 3) * 64;
        *reinterpret_cast<float4*>(rowp + c0)      = r0;
        *reinterpret_cast<float4*>(rowp + 32 + c0) = r1;
    }
}

extern "C" void kernel_launch(void* const* d_in, const int* in_sizes, int n_in_arrs,
                              void* d_out, int out_size, void* d_ws, size_t ws_size,
                              hipStream_t stream)
{
    const float* feat   = (const float*)d_in[0];
    const float* W      = (const float*)d_in[1];
    const float* gamma  = (const float*)d_in[2];
    const float* beta   = (const float*)d_in[3];
    const int*   pos    = (const int*)d_in[4];
    const int*   outpos = (const int*)d_in[5];

    const int n_in  = in_sizes[0] / 32;
    const int n_out = in_sizes[5] / 3;

    float* out   = (float*)d_out;
    float* stats = (float*)d_ws;
    int*   grid  = (int*)((char*)d_ws + STATS_BYTES);

    hipMemsetAsync(stats, 0, STATS_BYTES, stream);
    hipMemsetAsync(grid, 0xFF, (size_t)GRID_ELEMS * 4, stream);   // int -1

    const int prep_threads = (n_in + 1) * 4;      // covers both fused jobs
    prep_k<<<(prep_threads + 255) / 256, 256, 0, stream>>>(pos, grid, feat, n_in);
    conv_mfma_k<<<CONV_BLOCKS, 1024, 0, stream>>>(W, outpos, grid, stats, n_out, n_in);
    bn_relu_k<<<2048, 256, 0, stream>>>(out, stats, gamma, beta, n_out);
}